// Round 8
// baseline (492.445 us; speedup 1.0000x reference)
//
#include <hip/hip_runtime.h>
#include <hip/hip_fp16.h>

#define N_NODES_C 100000
#define N_EDGES_C 3200000
#define IN_F_C 10
#define HID_C 64
#define N_CLS_C 10
#define NEG_SLOPE_C 0.01f

#define NBUCK 98        // ceil(100000/1024); bucket = dst >> 10
#define BCAP  36864     // mean 32768, sigma ~180 -> +22 sigma headroom
#define TILE  2048      // edges per block in k_bucket (256 thr x 8)

// ---------------- pass 1: bucket partition, packed pairs, no global atomics per edge ----------------
__global__ __launch_bounds__(256) void k_bucket(const int* __restrict__ src,
                                                const int* __restrict__ dst,
                                                int* __restrict__ bcur,
                                                int* __restrict__ pairs, int E) {
    __shared__ int lcnt[NBUCK];
    __shared__ int gbase[NBUCK];
    const int t = threadIdx.x;
    for (int i = t; i < NBUCK; i += 256) lcnt[i] = 0;
    __syncthreads();
    const int base = blockIdx.x * TILE;
    int p[8], r[8], nb[8];
#pragma unroll
    for (int i = 0; i < 8; ++i) {
        int e = base + t + i * 256;
        if (e < E) {
            int s = src[e], d = dst[e];
            int b = d >> 10;
            nb[i] = b;
            p[i] = (s << 10) | (d & 1023);   // src<2^17, local dst<2^10
            r[i] = atomicAdd(&lcnt[b], 1);   // tile-local rank (LDS)
        }
    }
    __syncthreads();
    for (int i = t; i < NBUCK; i += 256)
        gbase[i] = lcnt[i] ? atomicAdd(&bcur[i], lcnt[i]) : 0;
    __syncthreads();
#pragma unroll
    for (int i = 0; i < 8; ++i) {
        int e = base + t + i * 256;
        if (e < E) {
            int pos = gbase[nb[i]] + r[i];
            if (pos < BCAP) pairs[nb[i] * BCAP + pos] = p[i];
        }
    }
}

// ---------------- tiny scan of 98 bucket sizes -> bucket base offsets ----------------
__global__ __launch_bounds__(128) void k_bscan(const int* __restrict__ bcur,
                                               int* __restrict__ bOff, int nbk) {
    __shared__ int s[128];
    int t = threadIdx.x;
    int v = (t < nbk) ? bcur[t] : 0;
    s[t] = v;
    __syncthreads();
    for (int off = 1; off < 128; off <<= 1) {
        int u = (t >= off) ? s[t - off] : 0;
        __syncthreads();
        s[t] += u;
        __syncthreads();
    }
    if (t < nbk) bOff[t] = s[t] - v;
}

// ---------------- pass 2: per-bucket hist + scan + row_ptr/dinv + placement, all LDS-local ----------------
__global__ __launch_bounds__(1024) void k_build(const int* __restrict__ pairs,
                                                const int* __restrict__ bcur,
                                                const int* __restrict__ bOff,
                                                int* __restrict__ row_ptr,
                                                float* __restrict__ dinv,
                                                int* __restrict__ col) {
    __shared__ int hist[1024];
    __shared__ int sm[1024];
    const int b = blockIdx.x;
    const int t = threadIdx.x;
    const int n = min(bcur[b], BCAP);
    const int base = bOff[b];
    const int* pp = pairs + b * BCAP;

    hist[t] = 0;
    __syncthreads();
    for (int i = t; i < n; i += 1024) atomicAdd(&hist[pp[i] & 1023], 1);
    __syncthreads();
    int c = hist[t];
    sm[t] = c;
    __syncthreads();
    for (int off = 1; off < 1024; off <<= 1) {
        int u = (t >= off) ? sm[t - off] : 0;
        __syncthreads();
        sm[t] += u;
        __syncthreads();
    }
    int rp = base + sm[t] - c;
    int gnode = (b << 10) + t;
    if (gnode < N_NODES_C) {
        row_ptr[gnode] = rp;
        dinv[gnode] = rsqrtf((float)(c + 1));
        if (gnode == N_NODES_C - 1) row_ptr[N_NODES_C] = rp + c;
    }
    __syncthreads();
    sm[t] = rp;
    __syncthreads();
    for (int i = t; i < n; i += 1024) {
        int p = pp[i];
        int idx = atomicAdd(&sm[p & 1023], 1);
        col[idx] = p >> 10;
    }
}

// ---------------- layer-1 transform: hs[n,f] = (x[n,:10] @ W1)[f] * dinv[n] ----------------
__global__ __launch_bounds__(256) void k_mm0(const float* __restrict__ x,
                                             const float* __restrict__ W,
                                             const float* __restrict__ dinv,
                                             __half* __restrict__ hs, int n) {
    __shared__ float4 W4[IN_F_C * 16];           // W4[k*16+f4] = W[k][4f4..4f4+3]
    const int t = threadIdx.x;
    for (int i = t; i < IN_F_C * 16; i += 256) {
        int k = i >> 4, f4 = i & 15;
        W4[i] = ((const float4*)(W + k * HID_C))[f4];
    }
    __syncthreads();
    int idx = blockIdx.x * 256 + t;              // node*16 + f4
    if (idx >= n * 16) return;
    int nn = idx >> 4, f4 = idx & 15;
    const float* row = x + nn * IN_F_C;
    float4 acc = make_float4(0.f, 0.f, 0.f, 0.f);
#pragma unroll
    for (int k = 0; k < IN_F_C; ++k) {
        float xv = row[k];
        float4 w = W4[k * 16 + f4];
        acc.x += xv * w.x; acc.y += xv * w.y; acc.z += xv * w.z; acc.w += xv * w.w;
    }
    float di = dinv[nn];
    ((__half2*)hs)[(nn << 5) + 2 * f4]     = __floats2half2_rn(acc.x * di, acc.y * di);
    ((__half2*)hs)[(nn << 5) + 2 * f4 + 1] = __floats2half2_rn(acc.z * di, acc.w * di);
}

// ---------------- lean gather (R5): fp16 rows, 2 edges/wave-step, fp16 act out ----------------
__global__ __launch_bounds__(256) void k_gather16(const int* __restrict__ row_ptr,
                                                  const int* __restrict__ col,
                                                  const __half2* __restrict__ hs,   // [n][32]
                                                  const float* __restrict__ dinv,
                                                  const float* __restrict__ b,
                                                  __half* __restrict__ act, int n) {
    const int lane = threadIdx.x & 63;
    const int half = lane >> 5;          // which edge of the pair
    const int fl   = lane & 31;          // feature-pair index (2 features)
    const int d = (blockIdx.x << 2) + (threadIdx.x >> 6);   // 4 waves / block
    if (d >= n) return;
    const int beg = row_ptr[d];
    const int end = row_ptr[d + 1];
    float2 acc = make_float2(0.f, 0.f);
    if (!half) {                          // self loop on half 0
        float2 v = __half22float2(hs[(d << 5) + fl]);
        acc.x = v.x; acc.y = v.y;
    }
    int e = beg;
    for (; e + 7 < end; e += 8) {         // 8 edges per iter (4 loads in flight/lane)
        int i0 = e + half, i1 = e + 2 + half, i2 = e + 4 + half, i3 = e + 6 + half;
        int s0 = col[i0], s1 = col[i1], s2 = col[i2], s3 = col[i3];
        float2 v0 = __half22float2(hs[(s0 << 5) + fl]);
        float2 v1 = __half22float2(hs[(s1 << 5) + fl]);
        float2 v2 = __half22float2(hs[(s2 << 5) + fl]);
        float2 v3 = __half22float2(hs[(s3 << 5) + fl]);
        acc.x += v0.x + v1.x + v2.x + v3.x;
        acc.y += v0.y + v1.y + v2.y + v3.y;
    }
    for (; e < end; e += 2) {
        int i = e + half;
        if (i < end) {
            float2 v = __half22float2(hs[(col[i] << 5) + fl]);
            acc.x += v.x; acc.y += v.y;
        }
    }
    acc.x += __shfl_xor(acc.x, 32, 64);
    acc.y += __shfl_xor(acc.y, 32, 64);
    if (!half) {
        float di = dinv[d];
        float2 bb = ((const float2*)b)[fl];
        float vx = acc.x * di + bb.x;
        float vy = acc.y * di + bb.y;
        vx = vx > 0.f ? vx : NEG_SLOPE_C * vx;
        vy = vy > 0.f ? vy : NEG_SLOPE_C * vy;
        ((__half2*)act)[(d << 5) + fl] = __floats2half2_rn(vx, vy);
    }
}

// ---------------- dense transform: hs[n,f'] = (act[n,:] @ W)[f'] * dinv[n], register-blocked ----------------
__global__ __launch_bounds__(256) void k_xform(const __half* __restrict__ act,
                                               const float* __restrict__ W,     // [64][64]
                                               const float* __restrict__ dinv,
                                               __half* __restrict__ hs, int n) {
    __shared__ float Ast[HID_C][68];     // transposed act tile: Ast[k][node], pad 68
    __shared__ float4 Wq[HID_C * 16];    // W row quads: Wq[k*16+f4] = W[k][4f4..]
    const int t = threadIdx.x;
    const int base = blockIdx.x * 64;

    for (int i = t; i < HID_C * 16; i += 256) Wq[i] = ((const float4*)W)[i];

    {   // stage act transposed, fp16 -> fp32
        const float2* aF2 = (const float2*)act;      // 4 halves
        int j = t & 63, qg = t >> 6;
#pragma unroll
        for (int qq = 0; qq < 4; ++qq) {
            int q = qg * 4 + qq;                     // 0..15
            int node = base + j;
            float2 raw = make_float2(0.f, 0.f);
            if (node < n) raw = aF2[node * 16 + q];
            __half2* hp = (__half2*)&raw;
            float2 lo = __half22float2(hp[0]);
            float2 hi = __half22float2(hp[1]);
            Ast[4 * q + 0][j] = lo.x;
            Ast[4 * q + 1][j] = lo.y;
            Ast[4 * q + 2][j] = hi.x;
            Ast[4 * q + 3][j] = hi.y;
        }
    }
    __syncthreads();

    const int f4 = t & 15, j4 = t >> 4;              // 4 features x 4 nodes per thread
    float4 s0 = make_float4(0.f,0.f,0.f,0.f), s1 = s0, s2 = s0, s3 = s0;
#pragma unroll
    for (int k = 0; k < HID_C; ++k) {
        float4 w = Wq[k * 16 + f4];
        float4 a = *(const float4*)&Ast[k][4 * j4];
        s0.x += a.x * w.x; s0.y += a.x * w.y; s0.z += a.x * w.z; s0.w += a.x * w.w;
        s1.x += a.y * w.x; s1.y += a.y * w.y; s1.z += a.y * w.z; s1.w += a.y * w.w;
        s2.x += a.z * w.x; s2.y += a.z * w.y; s2.z += a.z * w.z; s2.w += a.z * w.w;
        s3.x += a.w * w.x; s3.y += a.w * w.y; s3.z += a.w * w.z; s3.w += a.w * w.w;
    }
    float4 sv[4] = {s0, s1, s2, s3};
#pragma unroll
    for (int jj = 0; jj < 4; ++jj) {
        int node = base + 4 * j4 + jj;
        if (node < n) {
            float di = dinv[node];
            ((__half2*)hs)[(node << 5) + 2 * f4]     = __floats2half2_rn(sv[jj].x * di, sv[jj].y * di);
            ((__half2*)hs)[(node << 5) + 2 * f4 + 1] = __floats2half2_rn(sv[jj].z * di, sv[jj].w * di);
        }
    }
}

// ---------------- final FC: out[n,c] = act[n,:] @ Wfc + bfc, one thread per node ----------------
__global__ __launch_bounds__(256) void k_fc(const __half* __restrict__ act,
                                            const float* __restrict__ W,   // [64][10]
                                            const float* __restrict__ b,
                                            float* __restrict__ out, int n) {
    __shared__ float Wf[HID_C * N_CLS_C];
    const int t = threadIdx.x;
    for (int i = t; i < HID_C * N_CLS_C; i += 256) Wf[i] = W[i];
    __syncthreads();
    int node = blockIdx.x * 256 + t;
    if (node >= n) return;
    float s[N_CLS_C];
#pragma unroll
    for (int c = 0; c < N_CLS_C; ++c) s[c] = b[c];
    const float2* aF2 = (const float2*)act;
#pragma unroll
    for (int q = 0; q < 16; ++q) {
        float2 raw = aF2[node * 16 + q];
        __half2* hp = (__half2*)&raw;
        float2 lo = __half22float2(hp[0]);
        float2 hi = __half22float2(hp[1]);
        float a0 = lo.x, a1 = lo.y, a2 = hi.x, a3 = hi.y;
#pragma unroll
        for (int c = 0; c < N_CLS_C; ++c) {
            s[c] += a0 * Wf[(4*q+0)*N_CLS_C + c] + a1 * Wf[(4*q+1)*N_CLS_C + c]
                  + a2 * Wf[(4*q+2)*N_CLS_C + c] + a3 * Wf[(4*q+3)*N_CLS_C + c];
        }
    }
#pragma unroll
    for (int c = 0; c < N_CLS_C; ++c) out[node * N_CLS_C + c] = s[c];
}

extern "C" void kernel_launch(void* const* d_in, const int* in_sizes, int n_in,
                              void* d_out, int out_size, void* d_ws, size_t ws_size,
                              hipStream_t stream) {
    const float* x   = (const float*)d_in[0];
    const int*   ei  = (const int*)d_in[1];
    const float* W1  = (const float*)d_in[2];
    const float* b1  = (const float*)d_in[3];
    const float* W2  = (const float*)d_in[4];
    const float* b2  = (const float*)d_in[5];
    const float* W3  = (const float*)d_in[6];
    const float* b3  = (const float*)d_in[7];
    const float* Wfc = (const float*)d_in[8];
    const float* bfc = (const float*)d_in[9];
    float* out = (float*)d_out;

    const int N = N_NODES_C;
    const int E = N_EDGES_C;
    const int* src = ei;
    const int* dst = ei + E;

    // workspace carve-up (16B aligned)
    float*  dinv    = (float*)d_ws;                   // N
    int*    bcur    = (int*)(dinv + N);               // 128 (zeroed)
    int*    bOff    = bcur + 128;                     // 128
    int*    row_ptr = bOff + 128;                     // N+4
    int*    col     = row_ptr + N + 4;                // E
    int*    pairs   = col + E;                        // NBUCK*BCAP ints = 14.45 MB
    __half* hsA     = (__half*)pairs;                 // N*64 halves (aliases pairs; pairs dead by k_mm0)
    __half* actB    = (__half*)(pairs + (size_t)NBUCK * BCAP);   // N*64 halves

    int gN4  = (N + 3) / 4;                           // 25000
    int gM0  = (N * 16 + 255) / 256;                  // 6250
    int gBK  = (E + TILE - 1) / TILE;                 // 1563
    int gXF  = (N + 63) / 64;                         // 1563
    int gFC  = (N + 255) / 256;                       // 391

    // ---- CSR build (+ dinv), zero per-edge global atomics ----
    hipMemsetAsync(bcur, 0, 128 * sizeof(int), stream);
    k_bucket<<<gBK, 256, 0, stream>>>(src, dst, bcur, pairs, E);
    k_bscan<<<1, 128, 0, stream>>>(bcur, bOff, NBUCK);
    k_build<<<NBUCK, 1024, 0, stream>>>(pairs, bcur, bOff, row_ptr, dinv, col);

    // ---- layer 1 ----
    k_mm0<<<gM0, 256, 0, stream>>>(x, W1, dinv, hsA, N);
    k_gather16<<<gN4, 256, 0, stream>>>(row_ptr, col, (const __half2*)hsA, dinv, b1, actB, N);
    // ---- layer 2 ----
    k_xform<<<gXF, 256, 0, stream>>>(actB, W2, dinv, hsA, N);
    k_gather16<<<gN4, 256, 0, stream>>>(row_ptr, col, (const __half2*)hsA, dinv, b2, actB, N);
    // ---- layer 3 ----
    k_xform<<<gXF, 256, 0, stream>>>(actB, W3, dinv, hsA, N);
    k_gather16<<<gN4, 256, 0, stream>>>(row_ptr, col, (const __half2*)hsA, dinv, b3, actB, N);
    // ---- final FC ----
    k_fc<<<gFC, 256, 0, stream>>>(actB, Wfc, bfc, out, N);
}

// Round 9
// 430.554 us; speedup vs baseline: 1.1437x; 1.1437x over previous
//
#include <hip/hip_runtime.h>
#include <hip/hip_fp16.h>

#define N_NODES_C 100000
#define N_EDGES_C 3200000
#define IN_F_C 10
#define HID_C 64
#define N_CLS_C 10
#define NEG_SLOPE_C 0.01f

#define NBUCK 98        // ceil(100000/1024); bucket = dst >> 10
#define BCAP  36864     // mean 32768, sigma ~180 -> +22 sigma headroom
#define TILE  2048      // edges per block in k_bucket (256 thr x 8)

// ---------------- pass 1: bucket partition, packed pairs, no global atomics per edge ----------------
__global__ __launch_bounds__(256) void k_bucket(const int* __restrict__ src,
                                                const int* __restrict__ dst,
                                                int* __restrict__ bcur,
                                                int* __restrict__ pairs, int E) {
    __shared__ int lcnt[NBUCK];
    __shared__ int gbase[NBUCK];
    const int t = threadIdx.x;
    for (int i = t; i < NBUCK; i += 256) lcnt[i] = 0;
    __syncthreads();
    const int base = blockIdx.x * TILE;
    int p[8], r[8], nb[8];
#pragma unroll
    for (int i = 0; i < 8; ++i) {
        int e = base + t + i * 256;
        if (e < E) {
            int s = src[e], d = dst[e];
            int b = d >> 10;
            nb[i] = b;
            p[i] = (s << 10) | (d & 1023);
            r[i] = atomicAdd(&lcnt[b], 1);
        }
    }
    __syncthreads();
    for (int i = t; i < NBUCK; i += 256)
        gbase[i] = lcnt[i] ? atomicAdd(&bcur[i], lcnt[i]) : 0;
    __syncthreads();
#pragma unroll
    for (int i = 0; i < 8; ++i) {
        int e = base + t + i * 256;
        if (e < E) {
            int pos = gbase[nb[i]] + r[i];
            if (pos < BCAP) pairs[nb[i] * BCAP + pos] = p[i];
        }
    }
}

// ---------------- tiny scan of 98 bucket sizes ----------------
__global__ __launch_bounds__(128) void k_bscan(const int* __restrict__ bcur,
                                               int* __restrict__ bOff, int nbk) {
    __shared__ int s[128];
    int t = threadIdx.x;
    int v = (t < nbk) ? bcur[t] : 0;
    s[t] = v;
    __syncthreads();
    for (int off = 1; off < 128; off <<= 1) {
        int u = (t >= off) ? s[t - off] : 0;
        __syncthreads();
        s[t] += u;
        __syncthreads();
    }
    if (t < nbk) bOff[t] = s[t] - v;
}

// ---------------- pass 2: per-bucket hist + scan + row_ptr/dinv + placement ----------------
__global__ __launch_bounds__(1024) void k_build(const int* __restrict__ pairs,
                                                const int* __restrict__ bcur,
                                                const int* __restrict__ bOff,
                                                int* __restrict__ row_ptr,
                                                float* __restrict__ dinv,
                                                int* __restrict__ col) {
    __shared__ int hist[1024];
    __shared__ int sm[1024];
    const int b = blockIdx.x;
    const int t = threadIdx.x;
    const int n = min(bcur[b], BCAP);
    const int base = bOff[b];
    const int* pp = pairs + b * BCAP;

    hist[t] = 0;
    __syncthreads();
    for (int i = t; i < n; i += 1024) atomicAdd(&hist[pp[i] & 1023], 1);
    __syncthreads();
    int c = hist[t];
    sm[t] = c;
    __syncthreads();
    for (int off = 1; off < 1024; off <<= 1) {
        int u = (t >= off) ? sm[t - off] : 0;
        __syncthreads();
        sm[t] += u;
        __syncthreads();
    }
    int rp = base + sm[t] - c;
    int gnode = (b << 10) + t;
    if (gnode < N_NODES_C) {
        row_ptr[gnode] = rp;
        dinv[gnode] = rsqrtf((float)(c + 1));
        if (gnode == N_NODES_C - 1) row_ptr[N_NODES_C] = rp + c;
    }
    __syncthreads();
    sm[t] = rp;
    __syncthreads();
    for (int i = t; i < n; i += 1024) {
        int p = pp[i];
        int idx = atomicAdd(&sm[p & 1023], 1);
        col[idx] = p >> 10;
    }
}

// ---------------- layer-1 transform: hs = (x @ W1) * dinv ----------------
__global__ __launch_bounds__(256) void k_mm0(const float* __restrict__ x,
                                             const float* __restrict__ W,
                                             const float* __restrict__ dinv,
                                             __half* __restrict__ hs, int n) {
    __shared__ float4 W4[IN_F_C * 16];
    const int t = threadIdx.x;
    for (int i = t; i < IN_F_C * 16; i += 256) {
        int k = i >> 4, f4 = i & 15;
        W4[i] = ((const float4*)(W + k * HID_C))[f4];
    }
    __syncthreads();
    int idx = blockIdx.x * 256 + t;
    if (idx >= n * 16) return;
    int nn = idx >> 4, f4 = idx & 15;
    const float* row = x + nn * IN_F_C;
    float4 acc = make_float4(0.f, 0.f, 0.f, 0.f);
#pragma unroll
    for (int k = 0; k < IN_F_C; ++k) {
        float xv = row[k];
        float4 w = W4[k * 16 + f4];
        acc.x += xv * w.x; acc.y += xv * w.y; acc.z += xv * w.z; acc.w += xv * w.w;
    }
    float di = dinv[nn];
    ((__half2*)hs)[(nn << 5) + 2 * f4]     = __floats2half2_rn(acc.x * di, acc.y * di);
    ((__half2*)hs)[(nn << 5) + 2 * f4 + 1] = __floats2half2_rn(acc.z * di, acc.w * di);
}

// ---------------- fused gather + epilogue + next-layer transform (fp16 W, half8-packed) ----------------
// hs_next[d][f'] = ( lrelu((hs[d]+sum_e hs[col[e]])*dinv[d] + b) @ Wn )[f'] * dinv[d]
__global__ __launch_bounds__(256) void k_gft16(const int* __restrict__ row_ptr,
                                               const int* __restrict__ col,
                                               const __half* __restrict__ hsrc,
                                               const float* __restrict__ dinv,
                                               const float* __restrict__ bias,
                                               const float* __restrict__ Wn,   // [64][64]
                                               __half* __restrict__ hnext, int n) {
    __shared__ uint4 Wh[8 * HID_C];              // Wh[k8*64+f] = W[8k8..8k8+7][f] as 8 halves
    __shared__ __half2 rowh[4][32];              // act row fp16 per wave
    const int t = threadIdx.x;
    for (int i = t; i < 8 * HID_C; i += 256) {   // 512 entries, 2/thread
        int k8 = i >> 6, f = i & 63;
        __half2 h[4];
#pragma unroll
        for (int j = 0; j < 4; ++j)
            h[j] = __floats2half2_rn(Wn[(8 * k8 + 2 * j) * HID_C + f],
                                     Wn[(8 * k8 + 2 * j + 1) * HID_C + f]);
        Wh[i] = *(uint4*)h;
    }
    __syncthreads();

    const int lane = t & 63;
    const int wid  = t >> 6;
    const int g    = lane >> 4;                  // edge group 0..3
    const int fl   = lane & 15;                  // feature-quad
    const int d = (blockIdx.x << 2) + wid;
    if (d >= n) return;
    const int beg = row_ptr[d];
    const int end = row_ptr[d + 1];
    const float2* hsv = (const float2*)hsrc;

    float4 acc = make_float4(0.f, 0.f, 0.f, 0.f);
    if (g == 0) {                                // self loop
        float2 raw = hsv[(d << 4) + fl];
        float2 a0 = __half22float2(*(__half2*)&raw.x);
        float2 a1 = __half22float2(*(__half2*)&raw.y);
        acc = make_float4(a0.x, a0.y, a1.x, a1.y);
    }
    int e = beg;
    for (; e + 15 < end; e += 16) {              // 16 edges/iter, 4 loads in flight/lane
        int s0 = col[e + g];
        int s1 = col[e + 4 + g];
        int s2 = col[e + 8 + g];
        int s3 = col[e + 12 + g];
        float2 r0 = hsv[(s0 << 4) + fl];
        float2 r1 = hsv[(s1 << 4) + fl];
        float2 r2 = hsv[(s2 << 4) + fl];
        float2 r3 = hsv[(s3 << 4) + fl];
        float2 a0 = __half22float2(*(__half2*)&r0.x), a1 = __half22float2(*(__half2*)&r0.y);
        float2 b0 = __half22float2(*(__half2*)&r1.x), b1 = __half22float2(*(__half2*)&r1.y);
        float2 c0 = __half22float2(*(__half2*)&r2.x), c1 = __half22float2(*(__half2*)&r2.y);
        float2 d0 = __half22float2(*(__half2*)&r3.x), d1 = __half22float2(*(__half2*)&r3.y);
        acc.x += (a0.x + b0.x) + (c0.x + d0.x);
        acc.y += (a0.y + b0.y) + (c0.y + d0.y);
        acc.z += (a1.x + b1.x) + (c1.x + d1.x);
        acc.w += (a1.y + b1.y) + (c1.y + d1.y);
    }
    for (; e < end; e += 4) {
        int i = e + g;
        if (i < end) {
            float2 r = hsv[(col[i] << 4) + fl];
            float2 a0 = __half22float2(*(__half2*)&r.x);
            float2 a1 = __half22float2(*(__half2*)&r.y);
            acc.x += a0.x; acc.y += a0.y; acc.z += a1.x; acc.w += a1.y;
        }
    }
    acc.x += __shfl_xor(acc.x, 16, 64); acc.y += __shfl_xor(acc.y, 16, 64);
    acc.z += __shfl_xor(acc.z, 16, 64); acc.w += __shfl_xor(acc.w, 16, 64);
    acc.x += __shfl_xor(acc.x, 32, 64); acc.y += __shfl_xor(acc.y, 32, 64);
    acc.z += __shfl_xor(acc.z, 32, 64); acc.w += __shfl_xor(acc.w, 32, 64);

    const float di = dinv[d];
    if (g == 0) {                                // epilogue -> fp16 act row in LDS
        float4 bb = ((const float4*)bias)[fl];
        float4 v;
        v.x = acc.x * di + bb.x; v.y = acc.y * di + bb.y;
        v.z = acc.z * di + bb.z; v.w = acc.w * di + bb.w;
        v.x = v.x > 0.f ? v.x : NEG_SLOPE_C * v.x;
        v.y = v.y > 0.f ? v.y : NEG_SLOPE_C * v.y;
        v.z = v.z > 0.f ? v.z : NEG_SLOPE_C * v.z;
        v.w = v.w > 0.f ? v.w : NEG_SLOPE_C * v.w;
        rowh[wid][2 * fl]     = __floats2half2_rn(v.x, v.y);
        rowh[wid][2 * fl + 1] = __floats2half2_rn(v.z, v.w);
    }
    // wave-synchronous LDS (same wave writes & reads; compiler inserts lgkmcnt)
    {
        float s = 0.f;
        const uint4* rq = (const uint4*)rowh[wid];
#pragma unroll
        for (int k8 = 0; k8 < 8; ++k8) {
            uint4 wv = Wh[(k8 << 6) + lane];
            uint4 rv = rq[k8];                   // broadcast
            const __half2* wp = (const __half2*)&wv;
            const __half2* rp = (const __half2*)&rv;
#pragma unroll
            for (int j = 0; j < 4; ++j) {
                float2 wf = __half22float2(wp[j]);
                float2 rf = __half22float2(rp[j]);
                s += rf.x * wf.x + rf.y * wf.y;
            }
        }
        hnext[(d << 6) + lane] = __float2half(s * di);
    }
}

// ---------------- fused gather + epilogue + final FC (fp32 W) ----------------
__global__ __launch_bounds__(256) void k_gfc(const int* __restrict__ row_ptr,
                                             const int* __restrict__ col,
                                             const __half* __restrict__ hsrc,
                                             const float* __restrict__ dinv,
                                             const float* __restrict__ bias,
                                             const float* __restrict__ Wn,   // [64][10]
                                             const float* __restrict__ bn,
                                             float* __restrict__ out, int n) {
    __shared__ float4 Ws4[16 * N_CLS_C];         // Ws4[k4*10+f] = W[4k4..4k4+3][f]
    __shared__ float rowbuf[4][64];
    const int t = threadIdx.x;
    for (int i = t; i < 16 * N_CLS_C; i += 256) {
        int k4 = i / N_CLS_C, f = i - k4 * N_CLS_C;
        Ws4[i] = make_float4(Wn[(4 * k4 + 0) * N_CLS_C + f], Wn[(4 * k4 + 1) * N_CLS_C + f],
                             Wn[(4 * k4 + 2) * N_CLS_C + f], Wn[(4 * k4 + 3) * N_CLS_C + f]);
    }
    __syncthreads();

    const int lane = t & 63;
    const int wid  = t >> 6;
    const int g    = lane >> 4;
    const int fl   = lane & 15;
    const int d = (blockIdx.x << 2) + wid;
    if (d >= n) return;
    const int beg = row_ptr[d];
    const int end = row_ptr[d + 1];
    const float2* hsv = (const float2*)hsrc;

    float4 acc = make_float4(0.f, 0.f, 0.f, 0.f);
    if (g == 0) {
        float2 raw = hsv[(d << 4) + fl];
        float2 a0 = __half22float2(*(__half2*)&raw.x);
        float2 a1 = __half22float2(*(__half2*)&raw.y);
        acc = make_float4(a0.x, a0.y, a1.x, a1.y);
    }
    int e = beg;
    for (; e + 15 < end; e += 16) {
        int s0 = col[e + g];
        int s1 = col[e + 4 + g];
        int s2 = col[e + 8 + g];
        int s3 = col[e + 12 + g];
        float2 r0 = hsv[(s0 << 4) + fl];
        float2 r1 = hsv[(s1 << 4) + fl];
        float2 r2 = hsv[(s2 << 4) + fl];
        float2 r3 = hsv[(s3 << 4) + fl];
        float2 a0 = __half22float2(*(__half2*)&r0.x), a1 = __half22float2(*(__half2*)&r0.y);
        float2 b0 = __half22float2(*(__half2*)&r1.x), b1 = __half22float2(*(__half2*)&r1.y);
        float2 c0 = __half22float2(*(__half2*)&r2.x), c1 = __half22float2(*(__half2*)&r2.y);
        float2 d0 = __half22float2(*(__half2*)&r3.x), d1 = __half22float2(*(__half2*)&r3.y);
        acc.x += (a0.x + b0.x) + (c0.x + d0.x);
        acc.y += (a0.y + b0.y) + (c0.y + d0.y);
        acc.z += (a1.x + b1.x) + (c1.x + d1.x);
        acc.w += (a1.y + b1.y) + (c1.y + d1.y);
    }
    for (; e < end; e += 4) {
        int i = e + g;
        if (i < end) {
            float2 r = hsv[(col[i] << 4) + fl];
            float2 a0 = __half22float2(*(__half2*)&r.x);
            float2 a1 = __half22float2(*(__half2*)&r.y);
            acc.x += a0.x; acc.y += a0.y; acc.z += a1.x; acc.w += a1.y;
        }
    }
    acc.x += __shfl_xor(acc.x, 16, 64); acc.y += __shfl_xor(acc.y, 16, 64);
    acc.z += __shfl_xor(acc.z, 16, 64); acc.w += __shfl_xor(acc.w, 16, 64);
    acc.x += __shfl_xor(acc.x, 32, 64); acc.y += __shfl_xor(acc.y, 32, 64);
    acc.z += __shfl_xor(acc.z, 32, 64); acc.w += __shfl_xor(acc.w, 32, 64);

    const float di = dinv[d];
    if (g == 0) {
        float4 bb = ((const float4*)bias)[fl];
        float4 v;
        v.x = acc.x * di + bb.x; v.y = acc.y * di + bb.y;
        v.z = acc.z * di + bb.z; v.w = acc.w * di + bb.w;
        v.x = v.x > 0.f ? v.x : NEG_SLOPE_C * v.x;
        v.y = v.y > 0.f ? v.y : NEG_SLOPE_C * v.y;
        v.z = v.z > 0.f ? v.z : NEG_SLOPE_C * v.z;
        v.w = v.w > 0.f ? v.w : NEG_SLOPE_C * v.w;
        ((float4*)rowbuf[wid])[fl] = v;
    }
    if (lane < N_CLS_C) {
        float s = bn[lane];
        const float4* rb = (const float4*)rowbuf[wid];
#pragma unroll
        for (int k4 = 0; k4 < 16; ++k4) {
            float4 r4 = rb[k4];
            float4 w4 = Ws4[k4 * N_CLS_C + lane];
            s += r4.x * w4.x + r4.y * w4.y + r4.z * w4.z + r4.w * w4.w;
        }
        out[d * N_CLS_C + lane] = s;
    }
}

extern "C" void kernel_launch(void* const* d_in, const int* in_sizes, int n_in,
                              void* d_out, int out_size, void* d_ws, size_t ws_size,
                              hipStream_t stream) {
    const float* x   = (const float*)d_in[0];
    const int*   ei  = (const int*)d_in[1];
    const float* W1  = (const float*)d_in[2];
    const float* b1  = (const float*)d_in[3];
    const float* W2  = (const float*)d_in[4];
    const float* b2  = (const float*)d_in[5];
    const float* W3  = (const float*)d_in[6];
    const float* b3  = (const float*)d_in[7];
    const float* Wfc = (const float*)d_in[8];
    const float* bfc = (const float*)d_in[9];
    float* out = (float*)d_out;

    const int N = N_NODES_C;
    const int E = N_EDGES_C;
    const int* src = ei;
    const int* dst = ei + E;

    // workspace carve-up (16B aligned)
    float*  dinv    = (float*)d_ws;                   // N
    int*    bcur    = (int*)(dinv + N);               // 128 (zeroed)
    int*    bOff    = bcur + 128;                     // 128
    int*    row_ptr = bOff + 128;                     // N+4
    int*    col     = row_ptr + N + 4;                // E
    int*    pairs   = col + E;                        // NBUCK*BCAP ints
    __half* hsA     = (__half*)pairs;                 // N*64 halves (aliases pairs; dead by k_mm0)
    __half* hsB     = (__half*)(pairs + (size_t)NBUCK * BCAP);

    int gN4  = (N + 3) / 4;                           // 25000
    int gM0  = (N * 16 + 255) / 256;                  // 6250
    int gBK  = (E + TILE - 1) / TILE;                 // 1563

    // ---- CSR build (+ dinv) ----
    hipMemsetAsync(bcur, 0, 128 * sizeof(int), stream);
    k_bucket<<<gBK, 256, 0, stream>>>(src, dst, bcur, pairs, E);
    k_bscan<<<1, 128, 0, stream>>>(bcur, bOff, NBUCK);
    k_build<<<NBUCK, 1024, 0, stream>>>(pairs, bcur, bOff, row_ptr, dinv, col);

    // ---- layer 1 transform ----
    k_mm0<<<gM0, 256, 0, stream>>>(x, W1, dinv, hsA, N);

    // ---- fused gather+epilogue+transform chain ----
    k_gft16<<<gN4, 256, 0, stream>>>(row_ptr, col, hsA, dinv, b1, W2, hsB, N);
    k_gft16<<<gN4, 256, 0, stream>>>(row_ptr, col, hsB, dinv, b2, W3, hsA, N);
    k_gfc  <<<gN4, 256, 0, stream>>>(row_ptr, col, hsA, dinv, b3, Wfc, bfc, out, N);
}